// Round 11
// baseline (667.510 us; speedup 1.0000x reference)
//
#include <hip/hip_runtime.h>
#include <hip/hip_bf16.h>

// Grouped conv2d as implicit GEMM per group:
//   out[b*64+co][h][w] = sum_{ci,kh,kw} W[b*64+co][ci][kh][kw] * x[b*64+ci][h+kh-1][w+kw-1]
// bf16 MFMA (16x16x32), fp32 accumulate.
//
// R11 changes vs R7/R10 (four staging schemes all ~350us; cycle audit: no
// pipe >25% busy, machine ~70% idle at 8-16 waves/CU -> concurrency
// starvation from acc(64)+af-ring(64) VGPR):
//  - co-split waves: wave = (output row, co-half of 32). acc 64->32 VGPR,
//    af ring [4][2] = 32 VGPR. Block 256thr = 2 output rows x 2 co-halves.
//  - xs[4][66][32] = 16.9KB; __launch_bounds__(256,5) -> target 5 blocks/CU
//    = 20 waves/CU (62%) vs ~21% today.
//  - same verified swizzle (slot=(c>>1)&3, octet o at 8*(o^slot)), same
//    staging ping-pong (16 live floats), same epilogue algebra.
//  - grid 16384 = 32b x 128by x 4bx, bijective XCD swizzle.

typedef __bf16 bf16x8 __attribute__((ext_vector_type(8)));
typedef float  f32x4  __attribute__((ext_vector_type(4)));

#define NB 32
#define NH 256
#define NW 256
#define TILE_H 2
#define TILE_W 64
#define XROWS 4     // TILE_H + 2 (halo)
#define XCOLS 66    // TILE_W + 2
#define HWSZ ((size_t)NH * NW)

// ---------------------------------------------------------------------------
// Repack weights into MFMA A-fragment order:
//   pk[((b*9+tap)*4+mt)*2+kc][lane][j]  (bf16, 16B per lane)
// value = W[b*64 + mt*16 + (lane&15)][kc*32 + (lane>>4)*8 + j][tap]
// ---------------------------------------------------------------------------
__global__ void repack_weights_kernel(const float* __restrict__ wsrc,
                                      __bf16* __restrict__ pk) {
    int t = blockIdx.x * blockDim.x + threadIdx.x;
    if (t >= NB * 9 * 4 * 2 * 64) return;
    int lane = t & 63;
    int r = t >> 6;
    int kc = r & 1;  r >>= 1;
    int mt = r & 3;  r >>= 2;
    int tap = r % 9;
    int b   = r / 9;
    int co  = b * 64 + mt * 16 + (lane & 15);
    int ci0 = kc * 32 + (lane >> 4) * 8;
    bf16x8 v;
#pragma unroll
    for (int j = 0; j < 8; ++j) {
        v[j] = (__bf16)wsrc[(co * 64 + ci0 + j) * 9 + tap];
    }
    *reinterpret_cast<bf16x8*>(pk + (size_t)t * 8) = v;
}

// ---------------------------------------------------------------------------
// Main conv kernel. Block = (group b, 2 output rows, 64 cols), 4 waves.
// Wave wid: output row h0+(wid>>1), co-half ch=wid&1 (co in ch*32..ch*32+31).
// LDS xs[r][c][32]: octet o of column c at 8*(o ^ ((c>>1)&3)); kc phases 0,1.
// ---------------------------------------------------------------------------
__launch_bounds__(256, 5)
__global__ void conv_mfma_kernel(const float* __restrict__ x,
                                 const __bf16* __restrict__ pk,
                                 float* __restrict__ out) {
    __shared__ __align__(16) __bf16 xs[XROWS * XCOLS * 32];   // 16896 B

    // XCD-aware bijective swizzle: 16384 blocks, 8 XCDs -> 2048-chunk per XCD
    const int orig = blockIdx.x;
    const int wg   = (orig & 7) * 2048 + (orig >> 3);
    const int b    = wg >> 9;            // 0..31
    const int by   = (wg >> 2) & 127;    // 0..127
    const int bx   = wg & 3;             // 0..3
    const int h0   = by * TILE_H;
    const int w0   = bx * TILE_W;

    const int tid  = threadIdx.x;
    const int wid  = tid >> 6;           // 0..3
    const int lane = tid & 63;
    const int nl   = lane & 15;
    const int kgrp = lane >> 4;          // 0..3
    const int rloc = wid >> 1;           // output row within tile
    const int ch   = wid & 1;            // co-half

    const __bf16* pkb = pk + (size_t)b * 9 * 4096;

    // A-fragment ring: af[slot][mtl], slot = g&3, g = kc*9+tap, depth-2.
    bf16x8 af[4][2];
    auto load_af = [&](int g) {           // g in [0,18)
        const int tap = (g >= 9) ? g - 9 : g;
        const int kc  = (g >= 9) ? 1 : 0;
        const int sl  = g & 3;
#pragma unroll
        for (int mtl = 0; mtl < 2; ++mtl) {
            const int mtg = ch * 2 + mtl;
            af[sl][mtl] = *reinterpret_cast<const bf16x8*>(
                pkb + tap * 4096 + ((mtg * 2 + kc) * 64 + lane) * 8);
        }
    };
    load_af(0);
    load_af(1);

    f32x4 acc[2][4];   // [mtl][q]
#pragma unroll
    for (int mtl = 0; mtl < 2; ++mtl)
#pragma unroll
        for (int q = 0; q < 4; ++q)
            acc[mtl][q] = (f32x4){0.f, 0.f, 0.f, 0.f};

    // staging constants: thread = (column c = lane, ci-octet = wid)
    const int c    = lane;               // 0..63 -> w = w0-1+c
    const int w    = w0 - 1 + c;
    const int wcl  = min(max(w, 0), NW - 1);
    const bool wbad = (w != wcl);
    const int oct  = wid;
    const int sciw = ((oct ^ ((c >> 1) & 3)) * 8);   // swizzled octet offset

    // halo constants (threads 0..31: c=64,65; 4 rows x 2 sides x 4 oct)
    const int hr    = tid >> 3;              // 0..3
    const int hside = (tid >> 2) & 1;        // 0,1 -> c = 64,65
    const int hoct  = tid & 3;               // local ci octet
    const int hch   = 64 + hside;
    const int hw    = w0 + 63 + hside;
    const int hwc   = min(hw, NW - 1);

#pragma unroll
    for (int kc = 0; kc < 2; ++kc) {
        // ---- stage phase kc: 32 ci, coalesced scalar loads, b128 writes ----
        {
            const int cibase = b * 64 + kc * 32 + oct * 8;
            const float* colp = x + (size_t)cibase * HWSZ + wcl;

            float hv[8];
            if (tid < 32) {
                const int h  = h0 - 1 + hr;
                const int hc = min(max(h, 0), NH - 1);
                const float* src = x + ((size_t)(b * 64 + kc * 32 + hoct * 8) * NH + hc) * NW + hwc;
#pragma unroll
                for (int j = 0; j < 8; ++j) hv[j] = src[j * HWSZ];
                if (h != hc || hw != hwc) {
#pragma unroll
                    for (int j = 0; j < 8; ++j) hv[j] = 0.f;
                }
            }

            float va[8], vb[8];
            auto load8 = [&](int r, float* v) {   // r = 0..3
                const int h  = h0 - 1 + r;
                const int hc = min(max(h, 0), NH - 1);
                const float* src = colp + (size_t)hc * NW;
#pragma unroll
                for (int j = 0; j < 8; ++j) v[j] = src[j * HWSZ];
                if (wbad || h != hc) {
#pragma unroll
                    for (int j = 0; j < 8; ++j) v[j] = 0.f;
                }
            };
            auto store8 = [&](int r, const float* v) {
                bf16x8 o;
#pragma unroll
                for (int j = 0; j < 8; ++j) o[j] = (__bf16)v[j];
                *reinterpret_cast<bf16x8*>(xs + (r * XCOLS + c) * 32 + sciw) = o;
            };

            load8(0, va);
            load8(1, vb);
            store8(0, va); load8(2, va);
            store8(1, vb); load8(3, vb);
            store8(2, va);
            store8(3, vb);

            if (tid < 32) {
                bf16x8 o;
#pragma unroll
                for (int j = 0; j < 8; ++j) o[j] = (__bf16)hv[j];
                // slot(64)=slot(65)=0 -> octet position = hoct
                *reinterpret_cast<bf16x8*>(xs + (hr * XCOLS + hch) * 32 + hoct * 8) = o;
            }
        }
        __syncthreads();

        // ---- compute phase kc: 9 taps; af ring depth-2; 8 MFMA/tap ----
#pragma unroll
        for (int tap = 0; tap < 9; ++tap) {
            const int g = kc * 9 + tap;
            if (g + 2 < 18) load_af(g + 2);
            const int kh = tap / 3;
            const int kw = tap - kh * 3;
            const int rowbase = (rloc + kh) * XCOLS;
            const int fs = g & 3;
#pragma unroll
            for (int q = 0; q < 4; ++q) {
                const int cc   = q * 16 + nl + kw;          // 0..65
                const int slot = (cc >> 1) & 3;
                bf16x8 bfv = *reinterpret_cast<const bf16x8*>(
                    xs + (rowbase + cc) * 32 + ((kgrp ^ slot) * 8));
#pragma unroll
                for (int mtl = 0; mtl < 2; ++mtl)
                    acc[mtl][q] = __builtin_amdgcn_mfma_f32_16x16x32_bf16(
                        af[fs][mtl], bfv, acc[mtl][q], 0, 0, 0);
            }
        }
        if (kc == 0) __syncthreads();   // protect xs before phase-1 overwrite
    }

    // ---- epilogue: D lane layout col=lane&15, row=(lane>>4)*4+reg ----
    const int mrow = kgrp * 4;
    const int h = h0 + rloc;
#pragma unroll
    for (int mtl = 0; mtl < 2; ++mtl) {
#pragma unroll
        for (int q = 0; q < 4; ++q) {
            const int ww = w0 + q * 16 + nl;
#pragma unroll
            for (int rg = 0; rg < 4; ++rg) {
                const int co = (ch * 2 + mtl) * 16 + mrow + rg;
                out[((size_t)(b * 64 + co) * NH + h) * NW + ww] = acc[mtl][q][rg];
            }
        }
    }
}

extern "C" void kernel_launch(void* const* d_in, const int* in_sizes, int n_in,
                              void* d_out, int out_size, void* d_ws, size_t ws_size,
                              hipStream_t stream) {
    const float* x = (const float*)d_in[0];     // [1, 32*64, 256, 256] fp32
    const float* w = (const float*)d_in[1];     // [2048, 64, 3, 3] fp32
    float* out = (float*)d_out;                 // [1, 2048, 256, 256] fp32
    __bf16* pk = (__bf16*)d_ws;                 // 2.25 MB repacked bf16 weights

    {
        int total = NB * 9 * 4 * 2 * 64;        // 147456
        int blk = 256;
        int grid = (total + blk - 1) / blk;     // 576
        hipLaunchKernelGGL(repack_weights_kernel, dim3(grid), dim3(blk), 0, stream,
                           w, pk);
    }
    {
        dim3 grid(16384);                       // 32b x 128by x 4bx, swizzled
        hipLaunchKernelGGL(conv_mfma_kernel, grid, dim3(256), 0, stream,
                           x, pk, out);
    }
}

// Round 12
// 412.964 us; speedup vs baseline: 1.6164x; 1.6164x over previous
//
#include <hip/hip_runtime.h>
#include <hip/hip_bf16.h>

// Grouped conv2d as implicit GEMM per group:
//   out[b*64+co][h][w] = sum_{ci,kh,kw} W[b*64+co][ci][kh][kw] * x[b*64+ci][h+kh-1][w+kw-1]
// bf16 MFMA (16x16x32), fp32 accumulate.
//
// R12: VMEM-silent compute phases.
//  - co-split waves (R11 verified algebra): acc[2][4]=32 VGPR.
//  - af[9][2]=72 VGPR bulk-loaded once per kc phase (18 loads, compile-time
//    indices) -> the 9-tap loop has ZERO VMEM waits, so next-phase
//    global_load_lds staging rides the whole ~800cy compute without
//    poisoning af waits (R10's bug: in-order vmcnt made af prefetches
//    drain mid-compute gloads).
//  - ALL staging via global_load_lds (R10 verified), halo included via
//    size-4 variants into a 1.5KB LDS strip -> zero staging registers.
//  - 512 thr = 8 waves (4 rows x 2 co-halves); LDS 76KB -> 2 blocks/CU;
//    __launch_bounds__(512,4) caps VGPR at 128 (budget ~124).

typedef __bf16 bf16x8 __attribute__((ext_vector_type(8)));
typedef float  f32x4  __attribute__((ext_vector_type(4)));

#define NB 32
#define NH 256
#define NW 256
#define TILE_H 4
#define TILE_W 64
#define XROWS 6     // TILE_H + 2 (halo)
#define XCOLS 66    // col 0 and 65 are halo
#define HWSZ ((size_t)NH * NW)

template<int P> struct IC { static constexpr int v = P; };

__device__ __forceinline__ void gload16(const float* g, float* lds) {
    __builtin_amdgcn_global_load_lds(
        (const __attribute__((address_space(1))) unsigned int*)g,
        (__attribute__((address_space(3))) unsigned int*)lds, 16, 0, 0);
}
__device__ __forceinline__ void gload4(const float* g, float* lds) {
    __builtin_amdgcn_global_load_lds(
        (const __attribute__((address_space(1))) unsigned int*)g,
        (__attribute__((address_space(3))) unsigned int*)lds, 4, 0, 0);
}

// ---------------------------------------------------------------------------
// Repack weights into MFMA A-fragment order:
//   pk[((b*9+tap)*4+mt)*2+kc][lane][j]  (bf16, 16B per lane)
// value = W[b*64 + mt*16 + (lane&15)][kc*32 + (lane>>4)*8 + j][tap]
// ---------------------------------------------------------------------------
__global__ void repack_weights_kernel(const float* __restrict__ wsrc,
                                      __bf16* __restrict__ pk) {
    int t = blockIdx.x * blockDim.x + threadIdx.x;
    if (t >= NB * 9 * 4 * 2 * 64) return;
    int lane = t & 63;
    int r = t >> 6;
    int kc = r & 1;  r >>= 1;
    int mt = r & 3;  r >>= 2;
    int tap = r % 9;
    int b   = r / 9;
    int co  = b * 64 + mt * 16 + (lane & 15);
    int ci0 = kc * 32 + (lane >> 4) * 8;
    bf16x8 v;
#pragma unroll
    for (int j = 0; j < 8; ++j) {
        v[j] = (__bf16)wsrc[(co * 64 + ci0 + j) * 9 + tap];
    }
    *reinterpret_cast<bf16x8*>(pk + (size_t)t * 8) = v;
}

// ---------------------------------------------------------------------------
// Main conv kernel. Block = (group b, 4 output rows, 64 cols), 8 waves.
// Wave wid: row rloc = wid>>1, co-half ch = wid&1.
// scratch: [6][32ci][64w] fp32 (gload_lds, linear) + halo strip [2][6][32].
// xs: [r][c][32] bf16, octet o of col c at 8*(o ^ ((c>>1)&3)).
// ---------------------------------------------------------------------------
__launch_bounds__(512, 4)
__global__ void conv_mfma_kernel(const float* __restrict__ x,
                                 const __bf16* __restrict__ pk,
                                 float* __restrict__ out) {
    __shared__ __align__(16) __bf16 xs[XROWS * XCOLS * 32];    // 25344 B
    __shared__ __align__(16) float  scratch[XROWS * 32 * 64];  // 49152 B
    __shared__ __align__(16) float  shalo[2 * XROWS * 32];     // 1536 B

    // XCD-aware bijective swizzle: 8192 blocks, 8 XCDs -> 1024-chunk per XCD
    const int orig = blockIdx.x;
    const int wg   = (orig & 7) * 1024 + (orig >> 3);
    const int b    = wg >> 8;            // 0..31
    const int by   = (wg >> 2) & 63;     // 0..63
    const int bx   = wg & 3;             // 0..3
    const int h0   = by * TILE_H;
    const int w0   = bx * TILE_W;

    const int tid  = threadIdx.x;
    const int wid  = tid >> 6;           // 0..7
    const int lane = tid & 63;
    const int nl   = lane & 15;
    const int kgrp = lane >> 4;          // 0..3
    const int rloc = wid >> 1;           // output row 0..3
    const int ch   = wid & 1;            // co-half

    const __bf16* pkb = pk + (size_t)b * 9 * 4096;

    // af for one whole kc phase: [tap][mtl], 72 VGPR, compile-time indexed.
    bf16x8 af[9][2];
    auto load_af_bulk = [&](auto kcc) {
        constexpr int KC = decltype(kcc)::v;
#pragma unroll
        for (int t = 0; t < 9; ++t)
#pragma unroll
            for (int mtl = 0; mtl < 2; ++mtl)
                af[t][mtl] = *reinterpret_cast<const bf16x8*>(
                    pkb + t * 4096 + (((ch * 2 + mtl) * 2 + KC) * 64 + lane) * 8);
    };

    f32x4 acc[2][4];   // [mtl][q]
#pragma unroll
    for (int mtl = 0; mtl < 2; ++mtl)
#pragma unroll
        for (int q = 0; q < 4; ++q)
            acc[mtl][q] = (f32x4){0.f, 0.f, 0.f, 0.f};

    // ---- bulk gloads for phase kcv: 48 dwordx4 instrs over 8 waves ----
    auto issue_gload = [&](int kcv) {
#pragma unroll
        for (int m = 0; m < 6; ++m) {
            const int I  = wid * 6 + m;      // 0..47
            const int r  = I >> 3;           // 0..5
            const int cb = I & 7;            // 4-ci block
            const int hh = h0 - 1 + r;
            const int hc = min(max(hh, 0), NH - 1);
            const float* src = x
                + ((size_t)(b * 64 + kcv * 32 + cb * 4 + (lane >> 4)) * NH + hc) * NW
                + w0 + (lane & 15) * 4;
            gload16(src, scratch + (r * 32 + cb * 4) * 64);
        }
        // halo strips: wave 0 only, 6 x dword gloads (2 cols x 192 elems)
        if (wid == 0) {
#pragma unroll
            for (int hI = 0; hI < 6; ++hI) {
                const int side = hI & 1;
                const int seg  = hI >> 1;            // 0..2
                const int idx  = seg * 64 + lane;    // 0..191
                const int r    = idx >> 5;
                const int ci   = idx & 31;
                const int wcol = min(max(w0 - 1 + side * 65, 0), NW - 1);
                const int hh   = h0 - 1 + r;
                const int hc   = min(max(hh, 0), NH - 1);
                const float* src = x
                    + ((size_t)(b * 64 + kcv * 32 + ci) * NH + hc) * NW + wcol;
                gload4(src, shalo + side * 192 + seg * 64);
            }
        }
    };

    // ---- cvt: scratch/shalo (fp32) -> xs (bf16, swizzled) ----
    const int c    = lane;               // main col -> xs col c+1
    const int oct  = wid & 3;
    const int rset = wid >> 2;           // 0,1 -> rows 0-2 / 3-5
    auto cvt = [&]() {
#pragma unroll
        for (int rr2 = 0; rr2 < 3; ++rr2) {
            const int rr = rset * 3 + rr2;
            const int hh = h0 - 1 + rr;
            const bool z = (hh < 0) || (hh > NH - 1);
            float v[8];
#pragma unroll
            for (int j = 0; j < 8; ++j)
                v[j] = scratch[(rr * 32 + oct * 8 + j) * 64 + c];
            bf16x8 o8;
#pragma unroll
            for (int j = 0; j < 8; ++j) o8[j] = z ? (__bf16)0.f : (__bf16)v[j];
            const int cc = c + 1;
            *reinterpret_cast<bf16x8*>(
                xs + (rr * XCOLS + cc) * 32 + ((oct ^ ((cc >> 1) & 3)) * 8)) = o8;
        }
        if (tid < 48) {
            const int side = tid & 1;
            const int q2   = tid >> 1;       // 0..23
            const int rr   = q2 % 6;
            const int ho   = q2 / 6;         // octet 0..3
            const int hh   = h0 - 1 + rr;
            const int wv   = w0 - 1 + side * 65;
            const bool z = (hh < 0) || (hh > NH - 1) || (wv < 0) || (wv > NW - 1);
            float v[8];
#pragma unroll
            for (int j = 0; j < 8; ++j)
                v[j] = shalo[side * 192 + rr * 32 + ho * 8 + j];
            bf16x8 o8;
#pragma unroll
            for (int j = 0; j < 8; ++j) o8[j] = z ? (__bf16)0.f : (__bf16)v[j];
            const int cc = side ? 65 : 0;    // slot(0)=slot(65)=0
            *reinterpret_cast<bf16x8*>(xs + (rr * XCOLS + cc) * 32 + ho * 8) = o8;
        }
    };

    // ---- compute one kc phase: 9 taps, VMEM-silent (af all in regs) ----
    auto compute = [&]() {
#pragma unroll
        for (int tap = 0; tap < 9; ++tap) {
            const int kh = tap / 3;
            const int kw = tap - kh * 3;
            const int rowbase = (rloc + kh) * XCOLS;
#pragma unroll
            for (int q = 0; q < 4; ++q) {
                const int cc   = q * 16 + nl + kw;          // 0..65
                const int slot = (cc >> 1) & 3;
                bf16x8 bfv = *reinterpret_cast<const bf16x8*>(
                    xs + (rowbase + cc) * 32 + ((kgrp ^ slot) * 8));
#pragma unroll
                for (int mtl = 0; mtl < 2; ++mtl)
                    acc[mtl][q] = __builtin_amdgcn_mfma_f32_16x16x32_bf16(
                        af[tap][mtl], bfv, acc[mtl][q], 0, 0, 0);
            }
        }
    };

    // ---- driver ----
    load_af_bulk(IC<0>{});      // af oldest in vmcnt queue; in regs by tap0
    issue_gload(0);
    __syncthreads();            // drain: scratch/shalo ready
    cvt();
    __syncthreads();
    issue_gload(1);             // rides the whole compute<0>
    compute();
    __syncthreads();            // drain kc=1 gloads (landed during compute)
    cvt();
    __syncthreads();
    load_af_bulk(IC<1>{});      // only exposed af latency (~300cy, once)
    compute();

    // ---- epilogue: D lane layout col=lane&15, row=(lane>>4)*4+reg ----
    const int mrow = kgrp * 4;
    const int h = h0 + rloc;
#pragma unroll
    for (int mtl = 0; mtl < 2; ++mtl) {
#pragma unroll
        for (int q = 0; q < 4; ++q) {
            const int ww = w0 + q * 16 + nl;
#pragma unroll
            for (int rg = 0; rg < 4; ++rg) {
                const int co = (ch * 2 + mtl) * 16 + mrow + rg;
                out[((size_t)(b * 64 + co) * NH + h) * NW + ww] = acc[mtl][q][rg];
            }
        }
    }
}

extern "C" void kernel_launch(void* const* d_in, const int* in_sizes, int n_in,
                              void* d_out, int out_size, void* d_ws, size_t ws_size,
                              hipStream_t stream) {
    const float* x = (const float*)d_in[0];     // [1, 32*64, 256, 256] fp32
    const float* w = (const float*)d_in[1];     // [2048, 64, 3, 3] fp32
    float* out = (float*)d_out;                 // [1, 2048, 256, 256] fp32
    __bf16* pk = (__bf16*)d_ws;                 // 2.25 MB repacked bf16 weights

    {
        int total = NB * 9 * 4 * 2 * 64;        // 147456
        int blk = 256;
        int grid = (total + blk - 1) / blk;     // 576
        hipLaunchKernelGGL(repack_weights_kernel, dim3(grid), dim3(blk), 0, stream,
                           w, pk);
    }
    {
        dim3 grid(8192);                        // 32b x 64by x 4bx, swizzled
        hipLaunchKernelGGL(conv_mfma_kernel, grid, dim3(512), 0, stream,
                           x, pk, out);
    }
}

// Round 13
// 289.556 us; speedup vs baseline: 2.3053x; 1.4262x over previous
//
#include <hip/hip_runtime.h>
#include <hip/hip_bf16.h>

// Grouped conv2d as implicit GEMM per group:
//   out[b*64+co][h][w] = sum_{ci,kh,kw} W[b*64+co][ci][kh][kw] * x[b*64+ci][h+kh-1][w+kw-1]
// bf16 MFMA (16x16x32), fp32 accumulate.
//
// R13 = R7 (best verified: 348us rocprof, 108 VGPR, no spill) + ONE change:
//  - af broadcast through LDS via global_load_lds (ZERO register cost —
//    the register-safe form of the R9/R12 idea, both of which spilled):
//    per kc phase each wave issues 9 fire-and-forget 1KB gload16s copying
//    the 36 A-fragments into afs[36*512]; compute reads them with
//    lane-linear ds_read_b128 (0-conflict). Compute is fully VMEM-silent.
//    Per-CU af L2 traffic 9.4 -> 2.4 MB; per-tap af wait L2 -> LDS.
//  - everything else byte-identical to R7. LDS 26.1+36.9=63KB -> 2 blocks/CU
//    (R7 measured ~1.6 resident anyway).

typedef __bf16 bf16x8 __attribute__((ext_vector_type(8)));
typedef float  f32x4  __attribute__((ext_vector_type(4)));

#define NB 32
#define NH 256
#define NW 256
#define TILE_H 4
#define TILE_W 64
#define XROWS 6     // TILE_H + 2 (halo)
#define XCOLS 68    // TILE_W + 2, padded
#define HWSZ ((size_t)NH * NW)

__device__ __forceinline__ void gload16(const float* g, float* lds) {
    __builtin_amdgcn_global_load_lds(
        (const __attribute__((address_space(1))) unsigned int*)g,
        (__attribute__((address_space(3))) unsigned int*)lds, 16, 0, 0);
}

// ---------------------------------------------------------------------------
// Repack weights into MFMA A-fragment order:
//   pk[((b*9+tap)*4+mt)*2+kc][lane][j]  (bf16, 16B per lane)
// value = W[b*64 + mt*16 + (lane&15)][kc*32 + (lane>>4)*8 + j][tap]
// ---------------------------------------------------------------------------
__global__ void repack_weights_kernel(const float* __restrict__ wsrc,
                                      __bf16* __restrict__ pk) {
    int t = blockIdx.x * blockDim.x + threadIdx.x;
    if (t >= NB * 9 * 4 * 2 * 64) return;
    int lane = t & 63;
    int r = t >> 6;
    int kc = r & 1;  r >>= 1;
    int mt = r & 3;  r >>= 2;
    int tap = r % 9;
    int b   = r / 9;
    int co  = b * 64 + mt * 16 + (lane & 15);
    int ci0 = kc * 32 + (lane >> 4) * 8;
    bf16x8 v;
#pragma unroll
    for (int j = 0; j < 8; ++j) {
        v[j] = (__bf16)wsrc[(co * 64 + ci0 + j) * 9 + tap];
    }
    *reinterpret_cast<bf16x8*>(pk + (size_t)t * 8) = v;
}

// ---------------------------------------------------------------------------
// Main conv kernel. Block = (group b, 4 output rows, 64 output cols), 4 waves.
// xs: [r][c][32] bf16, octet of local ci o stored at 8*(o ^ ((c>>1)&3)).
// afs: 36 fragments (tap*4+mt) x 512 bf16, lane-linear; refilled per kc phase.
// ---------------------------------------------------------------------------
__launch_bounds__(256)
__global__ void conv_mfma_kernel(const float* __restrict__ x,
                                 const __bf16* __restrict__ pk,
                                 float* __restrict__ out) {
    __shared__ __align__(16) __bf16 xs[XROWS * XCOLS * 32];   // 26112 B
    __shared__ __align__(16) __bf16 afs[36 * 512];            // 36864 B

    // XCD-aware bijective swizzle: 8192 blocks, 8 XCDs
    const int orig = blockIdx.x;
    const int wg   = (orig & 7) * 1024 + (orig >> 3);
    const int b    = wg >> 8;            // 0..31
    const int by   = (wg >> 2) & 63;     // 0..63
    const int bx   = wg & 3;             // 0..3
    const int h0   = by * TILE_H;
    const int w0   = bx * TILE_W;

    const int tid  = threadIdx.x;
    const int wid  = tid >> 6;
    const int lane = tid & 63;
    const int nl   = lane & 15;
    const int kgrp = lane >> 4;          // 0..3

    const char* pkb = (const char*)(pk + (size_t)b * 9 * 4096);  // byte base

    // ---- af copy for phase kcv: 9 x 1KB gload16 per wave, zero registers ----
    auto issue_af = [&](int kcv) {
#pragma unroll
        for (int i = 0; i < 9; ++i) {
            const int f  = wid * 9 + i;       // fragment 0..35
            const int tp = f >> 2;
            const int mt = f & 3;
            const float* src = (const float*)(pkb + tp * 8192
                                              + (mt * 2 + kcv) * 1024 + lane * 16);
            gload16(src, (float*)((char*)afs + f * 1024));
        }
    };

    f32x4 acc[4][4];   // [mt][q]
#pragma unroll
    for (int mt = 0; mt < 4; ++mt)
#pragma unroll
        for (int q = 0; q < 4; ++q)
            acc[mt][q] = (f32x4){0.f, 0.f, 0.f, 0.f};

    // staging thread constants (main region: thread = column c = lane, oct = wid)
    const int c    = lane;               // 0..63 -> w = w0-1+c
    const int w    = w0 - 1 + c;
    const int wcl  = min(max(w, 0), NW - 1);
    const bool wbad = (w != wcl);
    const int sciw = ((wid ^ ((c >> 1) & 3)) * 8);   // swizzled octet offset

    // halo thread constants (threads 0..47: c=64,65)
    const int hr    = tid >> 3;              // 0..5
    const int hside = (tid >> 2) & 1;        // 0,1 -> c = 64,65
    const int hoct  = tid & 3;               // local ci octet
    const int hch   = 64 + hside;
    const int hw    = w0 + 63 + hside;
    const int hwc   = min(hw, NW - 1);

#pragma unroll
    for (int kc = 0; kc < 2; ++kc) {
        // ---- stage phase kc: af copy (fire-and-forget) + 32-ci x tile ----
        {
            issue_af(kc);

            const int cibase = b * 64 + kc * 32 + wid * 8;
            const float* colp = x + (size_t)cibase * HWSZ + wcl;

            // halo loads first (threads 0..47), store at end
            float hv[8];
            if (tid < 48) {
                const int h  = h0 - 1 + hr;
                const int hc = min(max(h, 0), NH - 1);
                const float* src = x + ((size_t)(b * 64 + kc * 32 + hoct * 8) * NH + hc) * NW + hwc;
#pragma unroll
                for (int j = 0; j < 8; ++j) hv[j] = src[j * HWSZ];
                if (h != hc || hw != hwc) {
#pragma unroll
                    for (int j = 0; j < 8; ++j) hv[j] = 0.f;
                }
            }

            float va[8], vb[8];
            auto load8 = [&](int r, float* v) {
                const int h  = h0 - 1 + r;
                const int hc = min(max(h, 0), NH - 1);
                const float* src = colp + (size_t)hc * NW;
#pragma unroll
                for (int j = 0; j < 8; ++j) v[j] = src[j * HWSZ];
                if (wbad || h != hc) {
#pragma unroll
                    for (int j = 0; j < 8; ++j) v[j] = 0.f;
                }
            };
            auto store8 = [&](int r, const float* v) {
                bf16x8 o;
#pragma unroll
                for (int j = 0; j < 8; ++j) o[j] = (__bf16)v[j];
                *reinterpret_cast<bf16x8*>(xs + (r * XCOLS + c) * 32 + sciw) = o;
            };

            load8(0, va);
            load8(1, vb);
            store8(0, va); load8(2, va);
            store8(1, vb); load8(3, vb);
            store8(2, va); load8(4, va);
            store8(3, vb); load8(5, vb);
            store8(4, va);
            store8(5, vb);

            if (tid < 48) {
                bf16x8 o;
#pragma unroll
                for (int j = 0; j < 8; ++j) o[j] = (__bf16)hv[j];
                // slot(64)=slot(65)=0 -> octet position = hoct
                *reinterpret_cast<bf16x8*>(xs + (hr * XCOLS + hch) * 32 + hoct * 8) = o;
            }
        }
        __syncthreads();    // drains vmcnt: afs + xs both ready

        // ---- compute phase kc: 9 taps, VMEM-silent; af via ds_read_b128 ----
#pragma unroll
        for (int tap = 0; tap < 9; ++tap) {
            bf16x8 afr[4];
#pragma unroll
            for (int mt = 0; mt < 4; ++mt)
                afr[mt] = *reinterpret_cast<const bf16x8*>(
                    afs + (tap * 4 + mt) * 512 + lane * 8);
            const int kh = tap / 3;
            const int kw = tap - kh * 3;
            const int rowbase = (wid + kh) * XCOLS;
#pragma unroll
            for (int q = 0; q < 4; ++q) {
                const int cc   = q * 16 + nl + kw;          // 0..65
                const int slot = (cc >> 1) & 3;
                bf16x8 bfv = *reinterpret_cast<const bf16x8*>(
                    xs + (rowbase + cc) * 32 + ((kgrp ^ slot) * 8));
#pragma unroll
                for (int mt = 0; mt < 4; ++mt)
                    acc[mt][q] = __builtin_amdgcn_mfma_f32_16x16x32_bf16(
                        afr[mt], bfv, acc[mt][q], 0, 0, 0);
            }
        }
        if (kc == 0) __syncthreads();   // protect xs/afs before phase-1 refill
    }

    // ---- epilogue: D lane layout col=lane&15, row=(lane>>4)*4+reg ----
    const int mrow = kgrp * 4;
    const int h = h0 + wid;
#pragma unroll
    for (int mt = 0; mt < 4; ++mt) {
#pragma unroll
        for (int q = 0; q < 4; ++q) {
            const int ww = w0 + q * 16 + nl;
#pragma unroll
            for (int rg = 0; rg < 4; ++rg) {
                const int co = mt * 16 + mrow + rg;
                out[((size_t)(b * 64 + co) * NH + h) * NW + ww] = acc[mt][q][rg];
            }
        }
    }
}

extern "C" void kernel_launch(void* const* d_in, const int* in_sizes, int n_in,
                              void* d_out, int out_size, void* d_ws, size_t ws_size,
                              hipStream_t stream) {
    const float* x = (const float*)d_in[0];     // [1, 32*64, 256, 256] fp32
    const float* w = (const float*)d_in[1];     // [2048, 64, 3, 3] fp32
    float* out = (float*)d_out;                 // [1, 2048, 256, 256] fp32
    __bf16* pk = (__bf16*)d_ws;                 // 2.25 MB repacked bf16 weights

    {
        int total = NB * 9 * 4 * 2 * 64;        // 147456
        int blk = 256;
        int grid = (total + blk - 1) / blk;     // 576
        hipLaunchKernelGGL(repack_weights_kernel, dim3(grid), dim3(blk), 0, stream,
                           w, pk);
    }
    {
        dim3 grid(8192);                        // 1D, swizzled in-kernel
        hipLaunchKernelGGL(conv_mfma_kernel, grid, dim3(256), 0, stream,
                           x, pk, out);
    }
}